// Round 3
// baseline (412.493 us; speedup 1.0000x reference)
//
#include <hip/hip_runtime.h>

// RingAttention: out = softmax(Q K^T) V (no scale), B=32 SQ=1024 SKV=8192 D=64, fp32 I/O.
// R3: 4-way KV split (1024 blocks -> 16 waves/CU, was 4) + conflict-free V^T staging
// (n-major stores, was 8-way conflicted) + merge kernel for the split combine.
// fp16 MFMA 32x32x16, Q split hi+lo, S^T formulation (softmax lane-local).

#define NBATCH 32
#define SQL 1024
#define SKVL 8192
#define DH 64
#define BM 128                 // q rows per block (4 waves x 32)
#define BN 64                  // kv rows per tile
#define KSTR 72                // K lds row stride in halfs
#define VSTR 72                // V^T lds row stride in halfs (36 dwords: b128 reads phase-optimal)

typedef _Float16 half8 __attribute__((ext_vector_type(8)));
typedef __fp16 fp16x2 __attribute__((ext_vector_type(2)));
typedef float floatx16 __attribute__((ext_vector_type(16)));
typedef unsigned int uint4v __attribute__((ext_vector_type(4)));

union F8U { uint4v u; half8 h; };

#if __has_builtin(__builtin_amdgcn_exp2f)
#define EXP2F(x) __builtin_amdgcn_exp2f(x)
#else
#define EXP2F(x) exp2f(x)
#endif

static __device__ __forceinline__ unsigned pk2(float a, float b) {
#if __has_builtin(__builtin_amdgcn_cvt_pkrtz)
  fp16x2 h = __builtin_amdgcn_cvt_pkrtz(a, b);
  return __builtin_bit_cast(unsigned, h);
#else
  union { _Float16 h[2]; unsigned u; } r;
  r.h[0] = (_Float16)a; r.h[1] = (_Float16)b; return r.u;
#endif
}

template<int NSPLIT>
__global__ __launch_bounds__(256, 4)
void ring_attn(const float* __restrict__ q, const float* __restrict__ k,
               const float* __restrict__ v, float* __restrict__ out,
               float* __restrict__ pO, float* __restrict__ pM, float* __restrict__ pL)
{
  constexpr int NT = SKVL / NSPLIT / BN;   // tiles per block
  __shared__ _Float16 Kl[2][BN * KSTR];
  __shared__ _Float16 Vt[2][DH * VSTR];

  const int tid  = threadIdx.x;
  const int lane = tid & 63;
  const int wv   = tid >> 6;
  const int l31  = lane & 31;
  const int hb   = lane >> 5;
  const int b8   = hb * 8;

  int split, batch, qb;
  if (NSPLIT == 4) {                 // bi = qb*128 + batch*4 + split
    split = blockIdx.x & 3;          // same (batch,split) class -> same XCD (bi mod 8 const)
    batch = (blockIdx.x >> 2) & 31;
    qb    = blockIdx.x >> 7;
  } else {
    split = 0;
    batch = blockIdx.x & 31;
    qb    = blockIdx.x >> 5;
  }

  const float* kp = k + ((size_t)batch * SKVL + (size_t)split * (SKVL / NSPLIT)) * DH;
  const float* vp = v + ((size_t)batch * SKVL + (size_t)split * (SKVL / NSPLIT)) * DH;

  // ---- Q: scale by log2(e), split hi+lo fp16 (B-operand frags: n=q=l31, k=d) ----
  const float* qp = q + ((size_t)batch * SQL + qb * BM + wv * 32 + l31) * DH;
  half8 qhi[4], qlo[4];
#pragma unroll
  for (int kt = 0; kt < 4; ++kt) {
    float4 a = *(const float4*)(qp + kt * 16 + b8);
    float4 c = *(const float4*)(qp + kt * 16 + b8 + 4);
    float xs[8] = {a.x, a.y, a.z, a.w, c.x, c.y, c.z, c.w};
#pragma unroll
    for (int j = 0; j < 8; ++j) {
      float x = xs[j] * 1.44269504088896340736f;
      _Float16 h = (_Float16)x;
      qhi[kt][j] = h;
      qlo[kt][j] = (_Float16)(x - (float)h);
    }
  }

  // K staging: thread -> row krt(+16*it), cols kc..kc+3 (fp32)
  const int krt = tid >> 4;
  const int kc  = (tid & 15) * 4;
  // V staging (n-major, conflict-free): thread -> rows vnr,vnr+1, cols vcg..vcg+7
  const int vnr = 2 * (tid & 31);
  const int vcg = 8 * (tid >> 5);

  float4 gk[4], ga0, ga1, gb0, gb1;
  // prefetch tile 0
#pragma unroll
  for (int it = 0; it < 4; ++it)
    gk[it] = *(const float4*)(kp + (size_t)(krt + it * 16) * DH + kc);
  ga0 = *(const float4*)(vp + (size_t)vnr * DH + vcg);
  ga1 = *(const float4*)(vp + (size_t)vnr * DH + vcg + 4);
  gb0 = *(const float4*)(vp + (size_t)(vnr + 1) * DH + vcg);
  gb1 = *(const float4*)(vp + (size_t)(vnr + 1) * DH + vcg + 4);

  floatx16 accO[2];
#pragma unroll
  for (int i = 0; i < 2; ++i)
#pragma unroll
    for (int r = 0; r < 16; ++r) accO[i][r] = 0.f;
  float m_run = -3.0e38f, l_run = 0.f;

  int buf = 0;
  for (int tile = 0; tile < NT; ++tile) {
    _Float16* Kb = Kl[buf];
    _Float16* Vb = Vt[buf];

    // ---- stage prefetched regs -> LDS[buf] ----
#pragma unroll
    for (int it = 0; it < 4; ++it) {
      uint2 w2 = make_uint2(pk2(gk[it].x, gk[it].y), pk2(gk[it].z, gk[it].w));
      *(uint2*)&Kb[(krt + it * 16) * KSTR + kc] = w2;
    }
    {
      float av[8] = {ga0.x, ga0.y, ga0.z, ga0.w, ga1.x, ga1.y, ga1.z, ga1.w};
      float bv[8] = {gb0.x, gb0.y, gb0.z, gb0.w, gb1.x, gb1.y, gb1.z, gb1.w};
#pragma unroll
      for (int i = 0; i < 8; ++i)   // bank = (36*(vcg+i) + tid&31) & 31 -> all 32 banks
        *(unsigned*)&Vb[(vcg + i) * VSTR + vnr] = pk2(av[i], bv[i]);
    }
    __syncthreads();

    // ---- prefetch next tile ----
    if (tile + 1 < NT) {
      const float* kn = kp + (size_t)(tile + 1) * BN * DH;
      const float* vn = vp + (size_t)(tile + 1) * BN * DH;
#pragma unroll
      for (int it = 0; it < 4; ++it)
        gk[it] = *(const float4*)(kn + (size_t)(krt + it * 16) * DH + kc);
      ga0 = *(const float4*)(vn + (size_t)vnr * DH + vcg);
      ga1 = *(const float4*)(vn + (size_t)vnr * DH + vcg + 4);
      gb0 = *(const float4*)(vn + (size_t)(vnr + 1) * DH + vcg);
      gb1 = *(const float4*)(vn + (size_t)(vnr + 1) * DH + vcg + 4);
    }

    // ---- S^T = K_tile · Q^T ----
    floatx16 st[2];
#pragma unroll
    for (int t = 0; t < 2; ++t)
#pragma unroll
      for (int r = 0; r < 16; ++r) st[t][r] = 0.f;
#pragma unroll
    for (int kt = 0; kt < 4; ++kt) {
#pragma unroll
      for (int t = 0; t < 2; ++t) {
        half8 kf = *(const half8*)&Kb[(t * 32 + l31) * KSTR + kt * 16 + b8];
        st[t] = __builtin_amdgcn_mfma_f32_32x32x16_f16(kf, qhi[kt], st[t], 0, 0, 0);
        st[t] = __builtin_amdgcn_mfma_f32_32x32x16_f16(kf, qlo[kt], st[t], 0, 0, 0);
      }
    }

    // ---- online softmax (lane owns q-row l31) ----
    float mx = -3.0e38f;
#pragma unroll
    for (int t = 0; t < 2; ++t)
#pragma unroll
      for (int r = 0; r < 16; ++r) mx = fmaxf(mx, st[t][r]);
    mx = fmaxf(mx, __shfl_xor(mx, 32, 64));
    float m_new = fmaxf(m_run, mx);
    float alpha = EXP2F(m_run - m_new);
    m_run = m_new;
    float sum = 0.f;
#pragma unroll
    for (int t = 0; t < 2; ++t)
#pragma unroll
      for (int r = 0; r < 16; ++r) {
        float p = EXP2F(st[t][r] - m_new);
        st[t][r] = p;
        sum += p;
      }
    sum += __shfl_xor(sum, 32, 64);
    l_run = alpha * l_run + sum;

    if (__any(alpha != 1.0f)) {      // skip rescale once max has stabilized
#pragma unroll
      for (int r = 0; r < 16; ++r) {
        int row = (r & 3) + 8 * (r >> 2) + 4 * hb;
        float ar = __shfl(alpha, row, 64);
        accO[0][r] *= ar;
        accO[1][r] *= ar;
      }
    }

    // ---- P·V ----
#pragma unroll
    for (int t = 0; t < 2; ++t) {
      unsigned P01 = pk2(st[t][0],  st[t][1]);
      unsigned P23 = pk2(st[t][2],  st[t][3]);
      unsigned P45 = pk2(st[t][4],  st[t][5]);
      unsigned P67 = pk2(st[t][6],  st[t][7]);
      unsigned P89 = pk2(st[t][8],  st[t][9]);
      unsigned PAB = pk2(st[t][10], st[t][11]);
      unsigned PCD = pk2(st[t][12], st[t][13]);
      unsigned PEF = pk2(st[t][14], st[t][15]);
      unsigned x01 = __shfl_xor(P01, 32, 64), x23 = __shfl_xor(P23, 32, 64);
      unsigned x45 = __shfl_xor(P45, 32, 64), x67 = __shfl_xor(P67, 32, 64);
      unsigned x89 = __shfl_xor(P89, 32, 64), xAB = __shfl_xor(PAB, 32, 64);
      unsigned xCD = __shfl_xor(PCD, 32, 64), xEF = __shfl_xor(PEF, 32, 64);
      F8U fe, fo;
      fe.u = uint4v{hb ? x45 : P01, hb ? x67 : P23, hb ? P45 : x01, hb ? P67 : x23};
      fo.u = uint4v{hb ? xCD : P89, hb ? xEF : PAB, hb ? PCD : x89, hb ? PEF : xAB};
#pragma unroll
      for (int ds = 0; ds < 2; ++ds) {
        half8 vf0 = *(const half8*)&Vb[(ds * 32 + l31) * VSTR + (2 * t) * 16 + b8];
        accO[ds] = __builtin_amdgcn_mfma_f32_32x32x16_f16(fe.h, vf0, accO[ds], 0, 0, 0);
        half8 vf1 = *(const half8*)&Vb[(ds * 32 + l31) * VSTR + (2 * t + 1) * 16 + b8];
        accO[ds] = __builtin_amdgcn_mfma_f32_32x32x16_f16(fo.h, vf1, accO[ds], 0, 0, 0);
      }
    }
    buf ^= 1;
  }

  const int rowbase = batch * SQL + qb * BM + wv * 32;
  if (NSPLIT == 1) {
    float linv = 1.0f / l_run;
    float* op = out + (size_t)rowbase * DH;
#pragma unroll
    for (int r = 0; r < 16; ++r) {
      int row = (r & 3) + 8 * (r >> 2) + 4 * hb;
      float lr = __shfl(linv, row, 64);
      op[(size_t)row * DH + l31]      = accO[0][r] * lr;
      op[(size_t)row * DH + 32 + l31] = accO[1][r] * lr;
    }
  } else {
    // unnormalized partials + (m,l) per q-row
    float* po = pO + ((size_t)split * NBATCH * SQL + rowbase) * DH;
#pragma unroll
    for (int r = 0; r < 16; ++r) {
      int row = (r & 3) + 8 * (r >> 2) + 4 * hb;
      po[(size_t)row * DH + l31]      = accO[0][r];
      po[(size_t)row * DH + 32 + l31] = accO[1][r];
    }
    if (hb == 0) {
      pM[(size_t)split * NBATCH * SQL + rowbase + l31] = m_run;
      pL[(size_t)split * NBATCH * SQL + rowbase + l31] = l_run;
    }
  }
}

__global__ __launch_bounds__(256)
void merge4(const float* __restrict__ pO, const float* __restrict__ pM,
            const float* __restrict__ pL, float* __restrict__ out)
{
  const int idx  = blockIdx.x * 256 + threadIdx.x;    // [b][row][d] flat
  const int rowg = idx >> 6;
  const size_t PLANE = (size_t)NBATCH * SQL * DH;     // 2097152
  const int    RPL   = NBATCH * SQL;                  // 32768
  float m0 = pM[rowg], m1 = pM[RPL + rowg], m2 = pM[2 * RPL + rowg], m3 = pM[3 * RPL + rowg];
  float mx = fmaxf(fmaxf(m0, m1), fmaxf(m2, m3));
  float w0 = EXP2F(m0 - mx), w1 = EXP2F(m1 - mx), w2 = EXP2F(m2 - mx), w3 = EXP2F(m3 - mx);
  float l = w0 * pL[rowg] + w1 * pL[RPL + rowg] + w2 * pL[2 * RPL + rowg] + w3 * pL[3 * RPL + rowg];
  float o = w0 * pO[idx] + w1 * pO[PLANE + idx] + w2 * pO[2 * PLANE + idx] + w3 * pO[3 * PLANE + idx];
  out[idx] = o / l;
}

extern "C" void kernel_launch(void* const* d_in, const int* in_sizes, int n_in,
                              void* d_out, int out_size, void* d_ws, size_t ws_size,
                              hipStream_t stream) {
  (void)in_sizes; (void)n_in; (void)out_size;
  const float* q = (const float*)d_in[0];
  const float* k = (const float*)d_in[1];
  const float* v = (const float*)d_in[2];
  float* out = (float*)d_out;

  const size_t PLANE = (size_t)NBATCH * SQL * DH;              // floats per split plane
  const size_t RPL   = (size_t)NBATCH * SQL;                   // rows per split
  const size_t need  = (4 * PLANE + 8 * RPL) * sizeof(float);  // 34.6 MB

  if (ws_size >= need) {
    float* pO = (float*)d_ws;
    float* pM = pO + 4 * PLANE;
    float* pL = pM + 4 * RPL;
    ring_attn<4><<<dim3(1024), dim3(256), 0, stream>>>(q, k, v, nullptr, pO, pM, pL);
    merge4<<<dim3((NBATCH * SQL * DH) / 256), dim3(256), 0, stream>>>(pO, pM, pL, out);
  } else {
    ring_attn<1><<<dim3(256), dim3(256), 0, stream>>>(q, k, v, out, nullptr, nullptr, nullptr);
  }
}

// Round 4
// 287.873 us; speedup vs baseline: 1.4329x; 1.4329x over previous
//
#include <hip/hip_runtime.h>

// RingAttention: out = softmax(Q K^T) V (no scale), B=32 SQ=1024 SKV=8192 D=64, fp32 I/O.
// R4: NSPLIT=4 (1024 blocks, occupancy verified R3) + conflict-free V^T staging
// (SQ_LDS_BANK_CONFLICT=0 verified R3) + NO cross-compute register prefetch and
// launch_bounds(256,3) — R3's (256,4) forced 128 total regs -> scratch spills
// (FETCH 952 MB, L3 thrash). Staging latency now hidden by TLP (3-4 blocks/CU).
// fp16 MFMA 32x32x16, Q split hi+lo, S^T formulation (softmax lane-local).

#define NBATCH 32
#define SQL 1024
#define SKVL 8192
#define DH 64
#define BM 128                 // q rows per block (4 waves x 32)
#define BN 64                  // kv rows per tile
#define KSTR 72                // K lds row stride in halfs
#define VSTR 72                // V^T lds row stride in halfs (36 dwords: b128 reads phase-optimal)

typedef _Float16 half8 __attribute__((ext_vector_type(8)));
typedef __fp16 fp16x2 __attribute__((ext_vector_type(2)));
typedef float floatx16 __attribute__((ext_vector_type(16)));
typedef unsigned int uint4v __attribute__((ext_vector_type(4)));

union F8U { uint4v u; half8 h; };

#if __has_builtin(__builtin_amdgcn_exp2f)
#define EXP2F(x) __builtin_amdgcn_exp2f(x)
#else
#define EXP2F(x) exp2f(x)
#endif

static __device__ __forceinline__ unsigned pk2(float a, float b) {
#if __has_builtin(__builtin_amdgcn_cvt_pkrtz)
  fp16x2 h = __builtin_amdgcn_cvt_pkrtz(a, b);
  return __builtin_bit_cast(unsigned, h);
#else
  union { _Float16 h[2]; unsigned u; } r;
  r.h[0] = (_Float16)a; r.h[1] = (_Float16)b; return r.u;
#endif
}

template<int NSPLIT>
__global__ __launch_bounds__(256, 3)
void ring_attn(const float* __restrict__ q, const float* __restrict__ k,
               const float* __restrict__ v, float* __restrict__ out,
               float* __restrict__ pO, float* __restrict__ pM, float* __restrict__ pL)
{
  constexpr int NT = SKVL / NSPLIT / BN;   // tiles per block
  __shared__ _Float16 Kl[2][BN * KSTR];
  __shared__ _Float16 Vt[2][DH * VSTR];

  const int tid  = threadIdx.x;
  const int lane = tid & 63;
  const int wv   = tid >> 6;
  const int l31  = lane & 31;
  const int hb   = lane >> 5;
  const int b8   = hb * 8;

  int split, batch, qb;
  if (NSPLIT == 4) {                 // bi = qb*128 + batch*4 + split
    split = blockIdx.x & 3;          // all 8 qb-sharers of a K/V slice -> same XCD
    batch = (blockIdx.x >> 2) & 31;
    qb    = blockIdx.x >> 7;
  } else {
    split = 0;
    batch = blockIdx.x & 31;
    qb    = blockIdx.x >> 5;
  }

  const float* kp = k + ((size_t)batch * SKVL + (size_t)split * (SKVL / NSPLIT)) * DH;
  const float* vp = v + ((size_t)batch * SKVL + (size_t)split * (SKVL / NSPLIT)) * DH;

  // ---- Q: scale by log2(e), split hi+lo fp16 (B-operand frags: n=q=l31, k=d) ----
  const float* qp = q + ((size_t)batch * SQL + qb * BM + wv * 32 + l31) * DH;
  half8 qhi[4], qlo[4];
#pragma unroll
  for (int kt = 0; kt < 4; ++kt) {
    float4 a = *(const float4*)(qp + kt * 16 + b8);
    float4 c = *(const float4*)(qp + kt * 16 + b8 + 4);
    float xs[8] = {a.x, a.y, a.z, a.w, c.x, c.y, c.z, c.w};
#pragma unroll
    for (int j = 0; j < 8; ++j) {
      float x = xs[j] * 1.44269504088896340736f;
      _Float16 h = (_Float16)x;
      qhi[kt][j] = h;
      qlo[kt][j] = (_Float16)(x - (float)h);
    }
  }

  // K staging: thread -> row krt(+16*it), cols kc..kc+3 (fp32)
  const int krt = tid >> 4;
  const int kc  = (tid & 15) * 4;
  // V staging (n-major, conflict-free): thread -> rows vnr,vnr+1, cols vcg..vcg+7
  const int vnr = 2 * (tid & 31);
  const int vcg = 8 * (tid >> 5);

  floatx16 accO[2];
#pragma unroll
  for (int i = 0; i < 2; ++i)
#pragma unroll
    for (int r = 0; r < 16; ++r) accO[i][r] = 0.f;
  float m_run = -3.0e38f, l_run = 0.f;

  int buf = 0;
  for (int tile = 0; tile < NT; ++tile) {
    _Float16* Kb = Kl[buf];
    _Float16* Vb = Vt[buf];
    const float* kt_p = kp + (size_t)tile * BN * DH;
    const float* vt_p = vp + (size_t)tile * BN * DH;

    // ---- stage: global -> regs (short-lived) -> pack fp16 -> LDS[buf] ----
    {
#pragma unroll
      for (int it = 0; it < 4; ++it) {
        float4 g = *(const float4*)(kt_p + (size_t)(krt + it * 16) * DH + kc);
        uint2 w2 = make_uint2(pk2(g.x, g.y), pk2(g.z, g.w));
        *(uint2*)&Kb[(krt + it * 16) * KSTR + kc] = w2;
      }
      float4 ga0 = *(const float4*)(vt_p + (size_t)vnr * DH + vcg);
      float4 ga1 = *(const float4*)(vt_p + (size_t)vnr * DH + vcg + 4);
      float4 gb0 = *(const float4*)(vt_p + (size_t)(vnr + 1) * DH + vcg);
      float4 gb1 = *(const float4*)(vt_p + (size_t)(vnr + 1) * DH + vcg + 4);
      float av[8] = {ga0.x, ga0.y, ga0.z, ga0.w, ga1.x, ga1.y, ga1.z, ga1.w};
      float bv[8] = {gb0.x, gb0.y, gb0.z, gb0.w, gb1.x, gb1.y, gb1.z, gb1.w};
#pragma unroll
      for (int i = 0; i < 8; ++i)   // bank = (4*(vcg+i) + tid&31) & 31 -> all 32 banks
        *(unsigned*)&Vb[(vcg + i) * VSTR + vnr] = pk2(av[i], bv[i]);
    }
    __syncthreads();

    // ---- S^T = K_tile · Q^T ----
    floatx16 st[2];
#pragma unroll
    for (int t = 0; t < 2; ++t)
#pragma unroll
      for (int r = 0; r < 16; ++r) st[t][r] = 0.f;
#pragma unroll
    for (int kt = 0; kt < 4; ++kt) {
#pragma unroll
      for (int t = 0; t < 2; ++t) {
        half8 kf = *(const half8*)&Kb[(t * 32 + l31) * KSTR + kt * 16 + b8];
        st[t] = __builtin_amdgcn_mfma_f32_32x32x16_f16(kf, qhi[kt], st[t], 0, 0, 0);
        st[t] = __builtin_amdgcn_mfma_f32_32x32x16_f16(kf, qlo[kt], st[t], 0, 0, 0);
      }
    }

    // ---- online softmax (lane owns q-row l31) ----
    float mx = -3.0e38f;
#pragma unroll
    for (int t = 0; t < 2; ++t)
#pragma unroll
      for (int r = 0; r < 16; ++r) mx = fmaxf(mx, st[t][r]);
    mx = fmaxf(mx, __shfl_xor(mx, 32, 64));
    float m_new = fmaxf(m_run, mx);
    float alpha = EXP2F(m_run - m_new);
    m_run = m_new;
    float sum = 0.f;
#pragma unroll
    for (int t = 0; t < 2; ++t)
#pragma unroll
      for (int r = 0; r < 16; ++r) {
        float p = EXP2F(st[t][r] - m_new);
        st[t][r] = p;
        sum += p;
      }
    sum += __shfl_xor(sum, 32, 64);
    l_run = alpha * l_run + sum;

    if (__any(alpha != 1.0f)) {      // skip rescale once max has stabilized
#pragma unroll
      for (int r = 0; r < 16; ++r) {
        int row = (r & 3) + 8 * (r >> 2) + 4 * hb;
        float ar = __shfl(alpha, row, 64);
        accO[0][r] *= ar;
        accO[1][r] *= ar;
      }
    }

    // ---- P·V ----
#pragma unroll
    for (int t = 0; t < 2; ++t) {
      unsigned P01 = pk2(st[t][0],  st[t][1]);
      unsigned P23 = pk2(st[t][2],  st[t][3]);
      unsigned P45 = pk2(st[t][4],  st[t][5]);
      unsigned P67 = pk2(st[t][6],  st[t][7]);
      unsigned P89 = pk2(st[t][8],  st[t][9]);
      unsigned PAB = pk2(st[t][10], st[t][11]);
      unsigned PCD = pk2(st[t][12], st[t][13]);
      unsigned PEF = pk2(st[t][14], st[t][15]);
      unsigned x01 = __shfl_xor(P01, 32, 64), x23 = __shfl_xor(P23, 32, 64);
      unsigned x45 = __shfl_xor(P45, 32, 64), x67 = __shfl_xor(P67, 32, 64);
      unsigned x89 = __shfl_xor(P89, 32, 64), xAB = __shfl_xor(PAB, 32, 64);
      unsigned xCD = __shfl_xor(PCD, 32, 64), xEF = __shfl_xor(PEF, 32, 64);
      F8U fe, fo;
      fe.u = uint4v{hb ? x45 : P01, hb ? x67 : P23, hb ? P45 : x01, hb ? P67 : x23};
      fo.u = uint4v{hb ? xCD : P89, hb ? xEF : PAB, hb ? PCD : x89, hb ? PEF : xAB};
#pragma unroll
      for (int ds = 0; ds < 2; ++ds) {
        half8 vf0 = *(const half8*)&Vb[(ds * 32 + l31) * VSTR + (2 * t) * 16 + b8];
        accO[ds] = __builtin_amdgcn_mfma_f32_32x32x16_f16(fe.h, vf0, accO[ds], 0, 0, 0);
        half8 vf1 = *(const half8*)&Vb[(ds * 32 + l31) * VSTR + (2 * t + 1) * 16 + b8];
        accO[ds] = __builtin_amdgcn_mfma_f32_32x32x16_f16(fo.h, vf1, accO[ds], 0, 0, 0);
      }
    }
    buf ^= 1;
  }

  const int rowbase = batch * SQL + qb * BM + wv * 32;
  if (NSPLIT == 1) {
    float linv = 1.0f / l_run;
    float* op = out + (size_t)rowbase * DH;
#pragma unroll
    for (int r = 0; r < 16; ++r) {
      int row = (r & 3) + 8 * (r >> 2) + 4 * hb;
      float lr = __shfl(linv, row, 64);
      op[(size_t)row * DH + l31]      = accO[0][r] * lr;
      op[(size_t)row * DH + 32 + l31] = accO[1][r] * lr;
    }
  } else {
    // unnormalized partials + (m,l) per q-row
    float* po = pO + ((size_t)split * NBATCH * SQL + rowbase) * DH;
#pragma unroll
    for (int r = 0; r < 16; ++r) {
      int row = (r & 3) + 8 * (r >> 2) + 4 * hb;
      po[(size_t)row * DH + l31]      = accO[0][r];
      po[(size_t)row * DH + 32 + l31] = accO[1][r];
    }
    if (hb == 0) {
      pM[(size_t)split * NBATCH * SQL + rowbase + l31] = m_run;
      pL[(size_t)split * NBATCH * SQL + rowbase + l31] = l_run;
    }
  }
}

__global__ __launch_bounds__(256)
void merge4(const float* __restrict__ pO, const float* __restrict__ pM,
            const float* __restrict__ pL, float* __restrict__ out)
{
  const int idx  = blockIdx.x * 256 + threadIdx.x;    // [b][row][d] flat
  const int rowg = idx >> 6;
  const size_t PLANE = (size_t)NBATCH * SQL * DH;     // 2097152
  const int    RPL   = NBATCH * SQL;                  // 32768
  float m0 = pM[rowg], m1 = pM[RPL + rowg], m2 = pM[2 * RPL + rowg], m3 = pM[3 * RPL + rowg];
  float mx = fmaxf(fmaxf(m0, m1), fmaxf(m2, m3));
  float w0 = EXP2F(m0 - mx), w1 = EXP2F(m1 - mx), w2 = EXP2F(m2 - mx), w3 = EXP2F(m3 - mx);
  float l = w0 * pL[rowg] + w1 * pL[RPL + rowg] + w2 * pL[2 * RPL + rowg] + w3 * pL[3 * RPL + rowg];
  float o = w0 * pO[idx] + w1 * pO[PLANE + idx] + w2 * pO[2 * PLANE + idx] + w3 * pO[3 * PLANE + idx];
  out[idx] = o / l;
}

extern "C" void kernel_launch(void* const* d_in, const int* in_sizes, int n_in,
                              void* d_out, int out_size, void* d_ws, size_t ws_size,
                              hipStream_t stream) {
  (void)in_sizes; (void)n_in; (void)out_size;
  const float* q = (const float*)d_in[0];
  const float* k = (const float*)d_in[1];
  const float* v = (const float*)d_in[2];
  float* out = (float*)d_out;

  const size_t PLANE = (size_t)NBATCH * SQL * DH;              // floats per split plane
  const size_t RPL   = (size_t)NBATCH * SQL;                   // rows per split
  const size_t need  = (4 * PLANE + 8 * RPL) * sizeof(float);  // 34.6 MB

  if (ws_size >= need) {
    float* pO = (float*)d_ws;
    float* pM = pO + 4 * PLANE;
    float* pL = pM + 4 * RPL;
    ring_attn<4><<<dim3(1024), dim3(256), 0, stream>>>(q, k, v, nullptr, pO, pM, pL);
    merge4<<<dim3((NBATCH * SQL * DH) / 256), dim3(256), 0, stream>>>(pO, pM, pL, out);
  } else {
    ring_attn<1><<<dim3(256), dim3(256), 0, stream>>>(q, k, v, out, nullptr, nullptr, nullptr);
  }
}

// Round 5
// 265.259 us; speedup vs baseline: 1.5551x; 1.0853x over previous
//
#include <hip/hip_runtime.h>

// RingAttention: out = softmax(Q K^T) V (no scale), B=32 SQ=1024 SKV=8192 D=64, fp32 I/O.
// R5: R3's software pipeline (register prefetch of tile t+1 hides L2 latency inside the
// wave) + R4's register budget (launch_bounds(256,3): cap ~170 regs -> no spills; R3's
// (256,4)=128 cap spilled with the prefetch live range). Conflict-free V^T staging
// (verified SQ_LDS_BANK_CONFLICT=0). NSPLIT=4, 1024 blocks. Vectorized merge.
// fp16 MFMA 32x32x16, Q split hi+lo, S^T formulation (softmax lane-local).

#define NBATCH 32
#define SQL 1024
#define SKVL 8192
#define DH 64
#define BM 128                 // q rows per block (4 waves x 32)
#define BN 64                  // kv rows per tile
#define KSTR 72                // K lds row stride in halfs
#define VSTR 72                // V^T lds row stride in halfs (36 dwords: b128 reads phase-optimal)

typedef _Float16 half8 __attribute__((ext_vector_type(8)));
typedef __fp16 fp16x2 __attribute__((ext_vector_type(2)));
typedef float floatx16 __attribute__((ext_vector_type(16)));
typedef float floatx4 __attribute__((ext_vector_type(4)));
typedef unsigned int uint4v __attribute__((ext_vector_type(4)));

union F8U { uint4v u; half8 h; };

#if __has_builtin(__builtin_amdgcn_exp2f)
#define EXP2F(x) __builtin_amdgcn_exp2f(x)
#else
#define EXP2F(x) exp2f(x)
#endif

static __device__ __forceinline__ unsigned pk2(float a, float b) {
#if __has_builtin(__builtin_amdgcn_cvt_pkrtz)
  fp16x2 h = __builtin_amdgcn_cvt_pkrtz(a, b);
  return __builtin_bit_cast(unsigned, h);
#else
  union { _Float16 h[2]; unsigned u; } r;
  r.h[0] = (_Float16)a; r.h[1] = (_Float16)b; return r.u;
#endif
}

template<int NSPLIT>
__global__ __launch_bounds__(256, 3)
void ring_attn(const float* __restrict__ q, const float* __restrict__ k,
               const float* __restrict__ v, float* __restrict__ out,
               float* __restrict__ pO, float* __restrict__ pM, float* __restrict__ pL)
{
  constexpr int NT = SKVL / NSPLIT / BN;   // tiles per block
  __shared__ _Float16 Kl[2][BN * KSTR];
  __shared__ _Float16 Vt[2][DH * VSTR];

  const int tid  = threadIdx.x;
  const int lane = tid & 63;
  const int wv   = tid >> 6;
  const int l31  = lane & 31;
  const int hb   = lane >> 5;
  const int b8   = hb * 8;

  int split, batch, qb;
  if (NSPLIT == 4) {                 // bi = qb*128 + batch*4 + split
    split = blockIdx.x & 3;          // all 8 qb-sharers of a K/V slice -> same XCD
    batch = (blockIdx.x >> 2) & 31;
    qb    = blockIdx.x >> 7;
  } else {
    split = 0;
    batch = blockIdx.x & 31;
    qb    = blockIdx.x >> 5;
  }

  const float* kp = k + ((size_t)batch * SKVL + (size_t)split * (SKVL / NSPLIT)) * DH;
  const float* vp = v + ((size_t)batch * SKVL + (size_t)split * (SKVL / NSPLIT)) * DH;

  // ---- Q: scale by log2(e), split hi+lo fp16 (B-operand frags: n=q=l31, k=d) ----
  const float* qp = q + ((size_t)batch * SQL + qb * BM + wv * 32 + l31) * DH;
  half8 qhi[4], qlo[4];
#pragma unroll
  for (int kt = 0; kt < 4; ++kt) {
    float4 a = *(const float4*)(qp + kt * 16 + b8);
    float4 c = *(const float4*)(qp + kt * 16 + b8 + 4);
    float xs[8] = {a.x, a.y, a.z, a.w, c.x, c.y, c.z, c.w};
#pragma unroll
    for (int j = 0; j < 8; ++j) {
      float x = xs[j] * 1.44269504088896340736f;
      _Float16 h = (_Float16)x;
      qhi[kt][j] = h;
      qlo[kt][j] = (_Float16)(x - (float)h);
    }
  }

  // K staging: thread -> row krt(+16*it), cols kc..kc+3 (fp32)
  const int krt = tid >> 4;
  const int kc  = (tid & 15) * 4;
  // V staging (n-major, conflict-free): thread -> rows vnr,vnr+1, cols vcg..vcg+7
  const int vnr = 2 * (tid & 31);
  const int vcg = 8 * (tid >> 5);

  float4 gk[4], ga0, ga1, gb0, gb1;
  // prefetch tile 0
#pragma unroll
  for (int it = 0; it < 4; ++it)
    gk[it] = *(const float4*)(kp + (size_t)(krt + it * 16) * DH + kc);
  ga0 = *(const float4*)(vp + (size_t)vnr * DH + vcg);
  ga1 = *(const float4*)(vp + (size_t)vnr * DH + vcg + 4);
  gb0 = *(const float4*)(vp + (size_t)(vnr + 1) * DH + vcg);
  gb1 = *(const float4*)(vp + (size_t)(vnr + 1) * DH + vcg + 4);

  floatx16 accO[2];
#pragma unroll
  for (int i = 0; i < 2; ++i)
#pragma unroll
    for (int r = 0; r < 16; ++r) accO[i][r] = 0.f;
  float m_run = -3.0e38f, l_run = 0.f;

  int buf = 0;
  for (int tile = 0; tile < NT; ++tile) {
    _Float16* Kb = Kl[buf];
    _Float16* Vb = Vt[buf];

    // ---- stage prefetched regs -> LDS[buf] ----
#pragma unroll
    for (int it = 0; it < 4; ++it) {
      uint2 w2 = make_uint2(pk2(gk[it].x, gk[it].y), pk2(gk[it].z, gk[it].w));
      *(uint2*)&Kb[(krt + it * 16) * KSTR + kc] = w2;
    }
    {
      float av[8] = {ga0.x, ga0.y, ga0.z, ga0.w, ga1.x, ga1.y, ga1.z, ga1.w};
      float bv[8] = {gb0.x, gb0.y, gb0.z, gb0.w, gb1.x, gb1.y, gb1.z, gb1.w};
#pragma unroll
      for (int i = 0; i < 8; ++i)   // bank = (36*(vcg+i) + tid&31) & 31 -> all 32 banks
        *(unsigned*)&Vb[(vcg + i) * VSTR + vnr] = pk2(av[i], bv[i]);
    }
    __syncthreads();

    // ---- issue next tile's loads (consumed at top of next iter: ~1000 cyc of hiding) ----
    if (tile + 1 < NT) {
      const float* kn = kp + (size_t)(tile + 1) * BN * DH;
      const float* vn = vp + (size_t)(tile + 1) * BN * DH;
#pragma unroll
      for (int it = 0; it < 4; ++it)
        gk[it] = *(const float4*)(kn + (size_t)(krt + it * 16) * DH + kc);
      ga0 = *(const float4*)(vn + (size_t)vnr * DH + vcg);
      ga1 = *(const float4*)(vn + (size_t)vnr * DH + vcg + 4);
      gb0 = *(const float4*)(vn + (size_t)(vnr + 1) * DH + vcg);
      gb1 = *(const float4*)(vn + (size_t)(vnr + 1) * DH + vcg + 4);
    }

    // ---- S^T = K_tile · Q^T ----
    floatx16 st[2];
#pragma unroll
    for (int t = 0; t < 2; ++t)
#pragma unroll
      for (int r = 0; r < 16; ++r) st[t][r] = 0.f;
#pragma unroll
    for (int kt = 0; kt < 4; ++kt) {
#pragma unroll
      for (int t = 0; t < 2; ++t) {
        half8 kf = *(const half8*)&Kb[(t * 32 + l31) * KSTR + kt * 16 + b8];
        st[t] = __builtin_amdgcn_mfma_f32_32x32x16_f16(kf, qhi[kt], st[t], 0, 0, 0);
        st[t] = __builtin_amdgcn_mfma_f32_32x32x16_f16(kf, qlo[kt], st[t], 0, 0, 0);
      }
    }

    // ---- online softmax (lane owns q-row l31) ----
    float mx = -3.0e38f;
#pragma unroll
    for (int t = 0; t < 2; ++t)
#pragma unroll
      for (int r = 0; r < 16; ++r) mx = fmaxf(mx, st[t][r]);
    mx = fmaxf(mx, __shfl_xor(mx, 32, 64));
    float m_new = fmaxf(m_run, mx);
    float alpha = EXP2F(m_run - m_new);
    m_run = m_new;
    float sum = 0.f;
#pragma unroll
    for (int t = 0; t < 2; ++t)
#pragma unroll
      for (int r = 0; r < 16; ++r) {
        float p = EXP2F(st[t][r] - m_new);
        st[t][r] = p;
        sum += p;
      }
    sum += __shfl_xor(sum, 32, 64);
    l_run = alpha * l_run + sum;

    if (__any(alpha != 1.0f)) {      // skip rescale once max has stabilized
#pragma unroll
      for (int r = 0; r < 16; ++r) {
        int row = (r & 3) + 8 * (r >> 2) + 4 * hb;
        float ar = __shfl(alpha, row, 64);
        accO[0][r] *= ar;
        accO[1][r] *= ar;
      }
    }

    // ---- P·V ----
#pragma unroll
    for (int t = 0; t < 2; ++t) {
      unsigned P01 = pk2(st[t][0],  st[t][1]);
      unsigned P23 = pk2(st[t][2],  st[t][3]);
      unsigned P45 = pk2(st[t][4],  st[t][5]);
      unsigned P67 = pk2(st[t][6],  st[t][7]);
      unsigned P89 = pk2(st[t][8],  st[t][9]);
      unsigned PAB = pk2(st[t][10], st[t][11]);
      unsigned PCD = pk2(st[t][12], st[t][13]);
      unsigned PEF = pk2(st[t][14], st[t][15]);
      unsigned x01 = __shfl_xor(P01, 32, 64), x23 = __shfl_xor(P23, 32, 64);
      unsigned x45 = __shfl_xor(P45, 32, 64), x67 = __shfl_xor(P67, 32, 64);
      unsigned x89 = __shfl_xor(P89, 32, 64), xAB = __shfl_xor(PAB, 32, 64);
      unsigned xCD = __shfl_xor(PCD, 32, 64), xEF = __shfl_xor(PEF, 32, 64);
      F8U fe, fo;
      fe.u = uint4v{hb ? x45 : P01, hb ? x67 : P23, hb ? P45 : x01, hb ? P67 : x23};
      fo.u = uint4v{hb ? xCD : P89, hb ? xEF : PAB, hb ? PCD : x89, hb ? PEF : xAB};
#pragma unroll
      for (int ds = 0; ds < 2; ++ds) {
        half8 vf0 = *(const half8*)&Vb[(ds * 32 + l31) * VSTR + (2 * t) * 16 + b8];
        accO[ds] = __builtin_amdgcn_mfma_f32_32x32x16_f16(fe.h, vf0, accO[ds], 0, 0, 0);
        half8 vf1 = *(const half8*)&Vb[(ds * 32 + l31) * VSTR + (2 * t + 1) * 16 + b8];
        accO[ds] = __builtin_amdgcn_mfma_f32_32x32x16_f16(fo.h, vf1, accO[ds], 0, 0, 0);
      }
    }
    buf ^= 1;
  }

  const int rowbase = batch * SQL + qb * BM + wv * 32;
  if (NSPLIT == 1) {
    float linv = 1.0f / l_run;
    float* op = out + (size_t)rowbase * DH;
#pragma unroll
    for (int r = 0; r < 16; ++r) {
      int row = (r & 3) + 8 * (r >> 2) + 4 * hb;
      float lr = __shfl(linv, row, 64);
      op[(size_t)row * DH + l31]      = accO[0][r] * lr;
      op[(size_t)row * DH + 32 + l31] = accO[1][r] * lr;
    }
  } else {
    // unnormalized partials + (m,l) per q-row
    float* po = pO + ((size_t)split * NBATCH * SQL + rowbase) * DH;
#pragma unroll
    for (int r = 0; r < 16; ++r) {
      int row = (r & 3) + 8 * (r >> 2) + 4 * hb;
      po[(size_t)row * DH + l31]      = accO[0][r];
      po[(size_t)row * DH + 32 + l31] = accO[1][r];
    }
    if (hb == 0) {
      pM[(size_t)split * NBATCH * SQL + rowbase + l31] = m_run;
      pL[(size_t)split * NBATCH * SQL + rowbase + l31] = l_run;
    }
  }
}

__global__ __launch_bounds__(256)
void merge4(const float* __restrict__ pO, const float* __restrict__ pM,
            const float* __restrict__ pL, float* __restrict__ out)
{
  const int i4   = blockIdx.x * 256 + threadIdx.x;    // float4 index
  const int rowg = i4 >> 4;                           // (i4*4)>>6
  const size_t PLANE4 = (size_t)NBATCH * SQL * DH / 4;  // 524288
  const int    RPL    = NBATCH * SQL;                   // 32768
  float m0 = pM[rowg], m1 = pM[RPL + rowg], m2 = pM[2 * RPL + rowg], m3 = pM[3 * RPL + rowg];
  float mx = fmaxf(fmaxf(m0, m1), fmaxf(m2, m3));
  float w0 = EXP2F(m0 - mx), w1 = EXP2F(m1 - mx), w2 = EXP2F(m2 - mx), w3 = EXP2F(m3 - mx);
  float l = w0 * pL[rowg] + w1 * pL[RPL + rowg] + w2 * pL[2 * RPL + rowg] + w3 * pL[3 * RPL + rowg];
  float li = 1.0f / l;
  const floatx4* p0 = (const floatx4*)pO;
  floatx4 o0 = p0[i4], o1 = p0[PLANE4 + i4], o2 = p0[2 * PLANE4 + i4], o3 = p0[3 * PLANE4 + i4];
  floatx4 o;
#pragma unroll
  for (int j = 0; j < 4; ++j)
    o[j] = (w0 * o0[j] + w1 * o1[j] + w2 * o2[j] + w3 * o3[j]) * li;
  ((floatx4*)out)[i4] = o;
}

extern "C" void kernel_launch(void* const* d_in, const int* in_sizes, int n_in,
                              void* d_out, int out_size, void* d_ws, size_t ws_size,
                              hipStream_t stream) {
  (void)in_sizes; (void)n_in; (void)out_size;
  const float* q = (const float*)d_in[0];
  const float* k = (const float*)d_in[1];
  const float* v = (const float*)d_in[2];
  float* out = (float*)d_out;

  const size_t PLANE = (size_t)NBATCH * SQL * DH;              // floats per split plane
  const size_t RPL   = (size_t)NBATCH * SQL;                   // rows per split
  const size_t need  = (4 * PLANE + 8 * RPL) * sizeof(float);  // 34.6 MB

  if (ws_size >= need) {
    float* pO = (float*)d_ws;
    float* pM = pO + 4 * PLANE;
    float* pL = pM + 4 * RPL;
    ring_attn<4><<<dim3(1024), dim3(256), 0, stream>>>(q, k, v, nullptr, pO, pM, pL);
    merge4<<<dim3((NBATCH * SQL * DH) / 1024), dim3(256), 0, stream>>>(pO, pM, pL, out);
  } else {
    ring_attn<1><<<dim3(256), dim3(256), 0, stream>>>(q, k, v, out, nullptr, nullptr, nullptr);
  }
}

// Round 6
// 251.890 us; speedup vs baseline: 1.6376x; 1.0531x over previous
//
#include <hip/hip_runtime.h>

// RingAttention: out = softmax(Q K^T) V (no scale), B=32 SQ=1024 SKV=8192 D=64, fp32 I/O.
// R6: R5 structure (NSPLIT=4, register prefetch, (256,3), conflict-free V^T staging,
// dbuf LDS) with two cuts aimed at the measured VALU-issue bound + 2-block residency:
//  - single-fp16 Q (qlo dropped): -16 VGPR, QK MFMA 16->8/tile. absmax est ~0.045.
//  - v_permlane32_swap_b32 for the P C-layout->A-layout exchange: 8 VALU swaps replace
//    16 ds_bpermute + 32 cndmask per tile (guarded; falls back to shfl path).
// fp16 MFMA 32x32x16, S^T formulation (softmax lane-local).

#define NBATCH 32
#define SQL 1024
#define SKVL 8192
#define DH 64
#define BM 128                 // q rows per block (4 waves x 32)
#define BN 64                  // kv rows per tile
#define KSTR 72                // K lds row stride in halfs
#define VSTR 72                // V^T lds row stride in halfs (36 dwords: b128 reads phase-optimal)

typedef _Float16 half8 __attribute__((ext_vector_type(8)));
typedef __fp16 fp16x2 __attribute__((ext_vector_type(2)));
typedef float floatx16 __attribute__((ext_vector_type(16)));
typedef float floatx4 __attribute__((ext_vector_type(4)));
typedef unsigned int uint4v __attribute__((ext_vector_type(4)));
typedef unsigned int uint2v __attribute__((ext_vector_type(2)));

union F8U { uint4v u; half8 h; };

#if __has_builtin(__builtin_amdgcn_exp2f)
#define EXP2F(x) __builtin_amdgcn_exp2f(x)
#else
#define EXP2F(x) exp2f(x)
#endif

static __device__ __forceinline__ unsigned pk2(float a, float b) {
#if __has_builtin(__builtin_amdgcn_cvt_pkrtz)
  fp16x2 h = __builtin_amdgcn_cvt_pkrtz(a, b);
  return __builtin_bit_cast(unsigned, h);
#else
  union { _Float16 h[2]; unsigned u; } r;
  r.h[0] = (_Float16)a; r.h[1] = (_Float16)b; return r.u;
#endif
}

#if __has_builtin(__builtin_amdgcn_permlane32_swap)
#define HAVE_PL32 1
// a' = [a.lo | b.lo], b' = [a.hi | b.hi]  (one VALU instr, both results)
static __device__ __forceinline__ void pl32(unsigned& a, unsigned& b) {
  uint2v r = __builtin_amdgcn_permlane32_swap(a, b, false, false);
  a = r[0]; b = r[1];
}
#else
#define HAVE_PL32 0
#endif

template<int NSPLIT>
__global__ __launch_bounds__(256, 3)
void ring_attn(const float* __restrict__ q, const float* __restrict__ k,
               const float* __restrict__ v, float* __restrict__ out,
               float* __restrict__ pO, float* __restrict__ pM, float* __restrict__ pL)
{
  constexpr int NT = SKVL / NSPLIT / BN;   // tiles per block
  __shared__ _Float16 Kl[2][BN * KSTR];
  __shared__ _Float16 Vt[2][DH * VSTR];

  const int tid  = threadIdx.x;
  const int lane = tid & 63;
  const int wv   = tid >> 6;
  const int l31  = lane & 31;
  const int hb   = lane >> 5;
  const int b8   = hb * 8;

  int split, batch, qb;
  if (NSPLIT == 4) {                 // bi = qb*128 + batch*4 + split
    split = blockIdx.x & 3;          // all 8 qb-sharers of a K/V slice -> same XCD
    batch = (blockIdx.x >> 2) & 31;
    qb    = blockIdx.x >> 7;
  } else {
    split = 0;
    batch = blockIdx.x & 31;
    qb    = blockIdx.x >> 5;
  }

  const float* kp = k + ((size_t)batch * SKVL + (size_t)split * (SKVL / NSPLIT)) * DH;
  const float* vp = v + ((size_t)batch * SKVL + (size_t)split * (SKVL / NSPLIT)) * DH;

  // ---- Q: scale by log2(e), round to fp16 (B-operand frags: n=q=l31, k=d) ----
  const float* qp = q + ((size_t)batch * SQL + qb * BM + wv * 32 + l31) * DH;
  half8 qf[4];
#pragma unroll
  for (int kt = 0; kt < 4; ++kt) {
    float4 a = *(const float4*)(qp + kt * 16 + b8);
    float4 c = *(const float4*)(qp + kt * 16 + b8 + 4);
    float xs[8] = {a.x, a.y, a.z, a.w, c.x, c.y, c.z, c.w};
#pragma unroll
    for (int j = 0; j < 8; ++j)
      qf[kt][j] = (_Float16)(xs[j] * 1.44269504088896340736f);
  }

  // K staging: thread -> row krt(+16*it), cols kc..kc+3 (fp32)
  const int krt = tid >> 4;
  const int kc  = (tid & 15) * 4;
  // V staging (n-major, conflict-free): thread -> rows vnr,vnr+1, cols vcg..vcg+7
  const int vnr = 2 * (tid & 31);
  const int vcg = 8 * (tid >> 5);

  float4 gk[4], ga0, ga1, gb0, gb1;
  // prefetch tile 0
#pragma unroll
  for (int it = 0; it < 4; ++it)
    gk[it] = *(const float4*)(kp + (size_t)(krt + it * 16) * DH + kc);
  ga0 = *(const float4*)(vp + (size_t)vnr * DH + vcg);
  ga1 = *(const float4*)(vp + (size_t)vnr * DH + vcg + 4);
  gb0 = *(const float4*)(vp + (size_t)(vnr + 1) * DH + vcg);
  gb1 = *(const float4*)(vp + (size_t)(vnr + 1) * DH + vcg + 4);

  floatx16 accO[2];
#pragma unroll
  for (int i = 0; i < 2; ++i)
#pragma unroll
    for (int r = 0; r < 16; ++r) accO[i][r] = 0.f;
  float m_run = -3.0e38f, l_run = 0.f;

  int buf = 0;
  for (int tile = 0; tile < NT; ++tile) {
    _Float16* Kb = Kl[buf];
    _Float16* Vb = Vt[buf];

    // ---- stage prefetched regs -> LDS[buf] ----
#pragma unroll
    for (int it = 0; it < 4; ++it) {
      uint2 w2 = make_uint2(pk2(gk[it].x, gk[it].y), pk2(gk[it].z, gk[it].w));
      *(uint2*)&Kb[(krt + it * 16) * KSTR + kc] = w2;
    }
    {
      float av[8] = {ga0.x, ga0.y, ga0.z, ga0.w, ga1.x, ga1.y, ga1.z, ga1.w};
      float bv[8] = {gb0.x, gb0.y, gb0.z, gb0.w, gb1.x, gb1.y, gb1.z, gb1.w};
#pragma unroll
      for (int i = 0; i < 8; ++i)   // bank = (36*(vcg+i) + tid&31) & 31 -> all 32 banks
        *(unsigned*)&Vb[(vcg + i) * VSTR + vnr] = pk2(av[i], bv[i]);
    }
    __syncthreads();

    // ---- issue next tile's loads (consumed at top of next iter) ----
    if (tile + 1 < NT) {
      const float* kn = kp + (size_t)(tile + 1) * BN * DH;
      const float* vn = vp + (size_t)(tile + 1) * BN * DH;
#pragma unroll
      for (int it = 0; it < 4; ++it)
        gk[it] = *(const float4*)(kn + (size_t)(krt + it * 16) * DH + kc);
      ga0 = *(const float4*)(vn + (size_t)vnr * DH + vcg);
      ga1 = *(const float4*)(vn + (size_t)vnr * DH + vcg + 4);
      gb0 = *(const float4*)(vn + (size_t)(vnr + 1) * DH + vcg);
      gb1 = *(const float4*)(vn + (size_t)(vnr + 1) * DH + vcg + 4);
    }

    // ---- S^T = K_tile · Q^T ----
    floatx16 st[2];
#pragma unroll
    for (int t = 0; t < 2; ++t)
#pragma unroll
      for (int r = 0; r < 16; ++r) st[t][r] = 0.f;
#pragma unroll
    for (int kt = 0; kt < 4; ++kt) {
#pragma unroll
      for (int t = 0; t < 2; ++t) {
        half8 kf = *(const half8*)&Kb[(t * 32 + l31) * KSTR + kt * 16 + b8];
        st[t] = __builtin_amdgcn_mfma_f32_32x32x16_f16(kf, qf[kt], st[t], 0, 0, 0);
      }
    }

    // ---- online softmax (lane owns q-row l31) ----
    float mx = -3.0e38f;
#pragma unroll
    for (int t = 0; t < 2; ++t)
#pragma unroll
      for (int r = 0; r < 16; ++r) mx = fmaxf(mx, st[t][r]);
    mx = fmaxf(mx, __shfl_xor(mx, 32, 64));
    float m_new = fmaxf(m_run, mx);
    float alpha = EXP2F(m_run - m_new);
    m_run = m_new;
    float sum = 0.f;
#pragma unroll
    for (int t = 0; t < 2; ++t)
#pragma unroll
      for (int r = 0; r < 16; ++r) {
        float p = EXP2F(st[t][r] - m_new);
        st[t][r] = p;
        sum += p;
      }
    sum += __shfl_xor(sum, 32, 64);
    l_run = alpha * l_run + sum;

    if (__any(alpha != 1.0f)) {      // skip rescale once max has stabilized
#pragma unroll
      for (int r = 0; r < 16; ++r) {
        int row = (r & 3) + 8 * (r >> 2) + 4 * hb;
        float ar = __shfl(alpha, row, 64);
        accO[0][r] *= ar;
        accO[1][r] *= ar;
      }
    }

    // ---- P·V: C-layout -> A-layout via permlane32_swap (or shfl fallback) ----
#pragma unroll
    for (int t = 0; t < 2; ++t) {
      unsigned P01 = pk2(st[t][0],  st[t][1]);
      unsigned P23 = pk2(st[t][2],  st[t][3]);
      unsigned P45 = pk2(st[t][4],  st[t][5]);
      unsigned P67 = pk2(st[t][6],  st[t][7]);
      unsigned P89 = pk2(st[t][8],  st[t][9]);
      unsigned PAB = pk2(st[t][10], st[t][11]);
      unsigned PCD = pk2(st[t][12], st[t][13]);
      unsigned PEF = pk2(st[t][14], st[t][15]);
      F8U fe, fo;
#if HAVE_PL32
      pl32(P01, P45); fe.u[0] = P01; fe.u[2] = P45;
      pl32(P23, P67); fe.u[1] = P23; fe.u[3] = P67;
      pl32(P89, PCD); fo.u[0] = P89; fo.u[2] = PCD;
      pl32(PAB, PEF); fo.u[1] = PAB; fo.u[3] = PEF;
#else
      unsigned x01 = __shfl_xor(P01, 32, 64), x23 = __shfl_xor(P23, 32, 64);
      unsigned x45 = __shfl_xor(P45, 32, 64), x67 = __shfl_xor(P67, 32, 64);
      unsigned x89 = __shfl_xor(P89, 32, 64), xAB = __shfl_xor(PAB, 32, 64);
      unsigned xCD = __shfl_xor(PCD, 32, 64), xEF = __shfl_xor(PEF, 32, 64);
      fe.u = uint4v{hb ? x45 : P01, hb ? x67 : P23, hb ? P45 : x01, hb ? P67 : x23};
      fo.u = uint4v{hb ? xCD : P89, hb ? xEF : PAB, hb ? PCD : x89, hb ? PEF : xAB};
#endif
#pragma unroll
      for (int ds = 0; ds < 2; ++ds) {
        half8 vf0 = *(const half8*)&Vb[(ds * 32 + l31) * VSTR + (2 * t) * 16 + b8];
        accO[ds] = __builtin_amdgcn_mfma_f32_32x32x16_f16(fe.h, vf0, accO[ds], 0, 0, 0);
        half8 vf1 = *(const half8*)&Vb[(ds * 32 + l31) * VSTR + (2 * t + 1) * 16 + b8];
        accO[ds] = __builtin_amdgcn_mfma_f32_32x32x16_f16(fo.h, vf1, accO[ds], 0, 0, 0);
      }
    }
    buf ^= 1;
  }

  const int rowbase = batch * SQL + qb * BM + wv * 32;
  if (NSPLIT == 1) {
    float linv = 1.0f / l_run;
    float* op = out + (size_t)rowbase * DH;
#pragma unroll
    for (int r = 0; r < 16; ++r) {
      int row = (r & 3) + 8 * (r >> 2) + 4 * hb;
      float lr = __shfl(linv, row, 64);
      op[(size_t)row * DH + l31]      = accO[0][r] * lr;
      op[(size_t)row * DH + 32 + l31] = accO[1][r] * lr;
    }
  } else {
    // unnormalized partials + (m,l) per q-row
    float* po = pO + ((size_t)split * NBATCH * SQL + rowbase) * DH;
#pragma unroll
    for (int r = 0; r < 16; ++r) {
      int row = (r & 3) + 8 * (r >> 2) + 4 * hb;
      po[(size_t)row * DH + l31]      = accO[0][r];
      po[(size_t)row * DH + 32 + l31] = accO[1][r];
    }
    if (hb == 0) {
      pM[(size_t)split * NBATCH * SQL + rowbase + l31] = m_run;
      pL[(size_t)split * NBATCH * SQL + rowbase + l31] = l_run;
    }
  }
}

__global__ __launch_bounds__(256)
void merge4(const float* __restrict__ pO, const float* __restrict__ pM,
            const float* __restrict__ pL, float* __restrict__ out)
{
  const int i4   = blockIdx.x * 256 + threadIdx.x;    // float4 index
  const int rowg = i4 >> 4;                           // (i4*4)>>6
  const size_t PLANE4 = (size_t)NBATCH * SQL * DH / 4;  // 524288
  const int    RPL    = NBATCH * SQL;                   // 32768
  float m0 = pM[rowg], m1 = pM[RPL + rowg], m2 = pM[2 * RPL + rowg], m3 = pM[3 * RPL + rowg];
  float mx = fmaxf(fmaxf(m0, m1), fmaxf(m2, m3));
  float w0 = EXP2F(m0 - mx), w1 = EXP2F(m1 - mx), w2 = EXP2F(m2 - mx), w3 = EXP2F(m3 - mx);
  float l = w0 * pL[rowg] + w1 * pL[RPL + rowg] + w2 * pL[2 * RPL + rowg] + w3 * pL[3 * RPL + rowg];
  float li = 1.0f / l;
  const floatx4* p0 = (const floatx4*)pO;
  floatx4 o0 = p0[i4], o1 = p0[PLANE4 + i4], o2 = p0[2 * PLANE4 + i4], o3 = p0[3 * PLANE4 + i4];
  floatx4 o;
#pragma unroll
  for (int j = 0; j < 4; ++j)
    o[j] = (w0 * o0[j] + w1 * o1[j] + w2 * o2[j] + w3 * o3[j]) * li;
  ((floatx4*)out)[i4] = o;
}

extern "C" void kernel_launch(void* const* d_in, const int* in_sizes, int n_in,
                              void* d_out, int out_size, void* d_ws, size_t ws_size,
                              hipStream_t stream) {
  (void)in_sizes; (void)n_in; (void)out_size;
  const float* q = (const float*)d_in[0];
  const float* k = (const float*)d_in[1];
  const float* v = (const float*)d_in[2];
  float* out = (float*)d_out;

  const size_t PLANE = (size_t)NBATCH * SQL * DH;              // floats per split plane
  const size_t RPL   = (size_t)NBATCH * SQL;                   // rows per split
  const size_t need  = (4 * PLANE + 8 * RPL) * sizeof(float);  // 34.6 MB

  if (ws_size >= need) {
    float* pO = (float*)d_ws;
    float* pM = pO + 4 * PLANE;
    float* pL = pM + 4 * RPL;
    ring_attn<4><<<dim3(1024), dim3(256), 0, stream>>>(q, k, v, nullptr, pO, pM, pL);
    merge4<<<dim3((NBATCH * SQL * DH) / 1024), dim3(256), 0, stream>>>(pO, pM, pL, out);
  } else {
    ring_attn<1><<<dim3(256), dim3(256), 0, stream>>>(q, k, v, out, nullptr, nullptr, nullptr);
  }
}